// Round 24
// baseline (102.232 us; speedup 1.0000x reference)
//
#include <hip/hip_runtime.h>
#include <math.h>

#define HH 240
#define WW 320
#define HWSZ (240*320)
#define NN 2

// Workspace layout (bytes)
#define OFF_BW1   0          // conv1 fp16 frags: 147456
#define OFF_BW3   147456     // conv3 fp16 frags: 73728
#define OFF_W2A   221184     // bases-GEMM A frags: 8192
#define OFF_COEFA 229376     // coef-GEMM A frags: 49152
#define OFF_BN    278528     // [sbr(64), bbr2(64), s3(64), o3(64)] f32 = 1024
#define OFF_FHF   279552     // feat NHWC fp16: 19660800
#define OFF_FHW   19940352   // wgt NHWC fp16: 19660800
#define OFF_U     39601152   // u NHWC fp16 (fused path only): 19660800
#define WS_FUSED  (OFF_U + 19660800)   // 59,261,952 B

typedef __attribute__((ext_vector_type(8))) _Float16 half8v;
typedef __attribute__((ext_vector_type(4))) _Float16 half4v;
typedef __attribute__((ext_vector_type(2))) _Float16 half2v;
typedef __attribute__((ext_vector_type(4))) float f32x4;

__device__ __forceinline__ half8v h8zero() {
    half8v z;
    #pragma unroll
    for (int j = 0; j < 8; ++j) z[j] = (_Float16)0.f;
    return z;
}

// ---------------- prep work (device fn; side-duty inside nhwc_k) ----------------
__device__ void do_prep(int id, const float* __restrict__ w1, const float* __restrict__ w3,
                        const float* __restrict__ w2, const float* __restrict__ coef,
                        const float* __restrict__ coef_bias,
                        const float* __restrict__ brg, const float* __restrict__ brb,
                        const float* __restrict__ brm, const float* __restrict__ brv,
                        const float* __restrict__ g3, const float* __restrict__ b3,
                        const float* __restrict__ m3, const float* __restrict__ v3,
                        float* __restrict__ ws) {
    _Float16* hw = (_Float16*)ws;

    if (id < 9216) {    // conv1 frags: frag = g*4 + m, g = cc*9 + t
        int l = id & 63; int f = id >> 6;
        int m = f & 3;   int g = f >> 2;
        int t = g % 9, cc = g / 9;
        _Float16* dst = hw + OFF_BW1/2 + (size_t)(g*4 + m)*512 + l*8;
        #pragma unroll
        for (int j = 0; j < 8; ++j) {
            int ci = cc*32 + (l>>4)*8 + j;
            int co = m*16 + (l&15);
            dst[j] = (_Float16)w1[(co*128 + ci)*9 + t];
        }
        return;
    }
    id -= 9216;
    if (id < 4608) {    // conv3 frags
        int l = id & 63; int f = id >> 6;
        int m = f & 3;   int g = f >> 2;
        int t = g % 9, cc = g / 9;
        _Float16* dst = hw + OFF_BW3/2 + (size_t)(g*4 + m)*512 + l*8;
        #pragma unroll
        for (int j = 0; j < 8; ++j) {
            int ci = cc*32 + (l>>4)*8 + j;
            int co = m*16 + (l&15);
            dst[j] = (_Float16)w3[(co*64 + ci)*9 + t];
        }
        return;
    }
    id -= 4608;
    if (id < 512) {     // W2A: A[row=j 54pad64][k=c 64]
        int l = id & 63; int f = id >> 6;
        int mf = f & 3, kc = f >> 2;
        int row = mf*16 + (l & 15);
        _Float16* dst = hw + OFF_W2A/2 + (size_t)((kc*4 + mf)*64 + l)*8;
        #pragma unroll
        for (int j = 0; j < 8; ++j) {
            int k = kc*32 + (l>>4)*8 + j;
            dst[j] = (row < 54) ? (_Float16)w2[row*64 + k] : (_Float16)0.f;
        }
        return;
    }
    id -= 512;
    if (id < 3072) {    // COEFA: k-order cg*96 + m_local*16 + c_local
        int l = id & 63; int f = id >> 6;
        int ocf = f & 3; int g2 = f >> 2;
        int ch = g2 % 3, cg = g2 / 3;
        int oc = ocf*16 + (l & 15);
        _Float16* dst = hw + OFF_COEFA/2 + (size_t)((g2*4 + ocf)*64 + l)*8;
        #pragma unroll
        for (int j = 0; j < 8; ++j) {
            int k32 = (l>>4)*8 + j;
            int m = ch*2 + (k32 >> 4);
            int c = cg*16 + (k32 & 15);
            dst[j] = (_Float16)coef[oc*384 + c*6 + m];
        }
        return;
    }
    id -= 3072;
    if (id < 64) {
        float s = brg[id] * rsqrtf(brv[id] + 1e-5f);
        ws[OFF_BN/4 + id]      = s;
        ws[OFF_BN/4 + 64 + id] = coef_bias[id]*s + brb[id] - brm[id]*s;
        return;
    }
    id -= 64;
    if (id < 64) {
        float s = g3[id] * rsqrtf(v3[id] + 1e-5f);
        ws[OFF_BN/4 + 128 + id] = s;
        ws[OFF_BN/4 + 192 + id] = b3[id] - m3[id]*s;
    }
}

// ---------------- NCHW f32 -> NHWC fp16 transpose + prep side-duty ----------------
__global__ void nhwc_k(const float* __restrict__ feat, const float* __restrict__ wgt,
                       _Float16* __restrict__ fhf, _Float16* __restrict__ fhw,
                       const float* __restrict__ w1, const float* __restrict__ w3,
                       const float* __restrict__ w2, const float* __restrict__ coef,
                       const float* __restrict__ coef_bias,
                       const float* __restrict__ brg, const float* __restrict__ brb,
                       const float* __restrict__ brm, const float* __restrict__ brv,
                       const float* __restrict__ g3, const float* __restrict__ b3,
                       const float* __restrict__ m3, const float* __restrict__ v3,
                       float* __restrict__ ws) {
    __shared__ float L[64][65];
    const int tid = threadIdx.x;

    const int bid = blockIdx.y * 5 + blockIdx.x;
    if (blockIdx.z == 0 && bid < 69)
        do_prep(bid*256 + tid, w1, w3, w2, coef, coef_bias,
                brg, brb, brm, brv, g3, b3, m3, v3, ws);

    const int xb = blockIdx.x * 64, y = blockIdx.y;
    const int n = blockIdx.z >> 1, w = blockIdx.z & 1;
    const float* src = (w ? wgt : feat) + (size_t)n*64*HWSZ + y*WW + xb;
    _Float16* dst = (w ? fhw : fhf) + ((size_t)n*HWSZ + y*WW + xb) * 64;
    const int lx = tid & 63, c4 = tid >> 6;
    #pragma unroll
    for (int k = 0; k < 16; ++k) {
        int c = c4*16 + k;
        L[c][lx] = src[(size_t)c*HWSZ + lx];
    }
    __syncthreads();
    const int x = tid >> 3, c0 = (tid & 7) * 8;
    #pragma unroll
    for (int h = 0; h < 2; ++h) {
        int xx = x + h*32;
        half8v v;
        #pragma unroll
        for (int j = 0; j < 8; ++j) v[j] = (_Float16)L[c0 + j][xx];
        *(half8v*)&dst[xx*64 + c0] = v;
    }
}

// ---------------- FUSED conv1 + fuse2: t stays in LDS; LDS <= 32256 (5 blocks/CU) ----------------
// BSH compacted to [128][58] (116B rows, 29-dword stride -> conflict-free u16):
// idx = px*58 + tap*6 + (m&1)*3 + (m>>1). Pad rows jb>=54 are SKIPPED (R23 bug:
// m=6 aliased the m=1 slot in the 3-wide groups — pad slots were load-bearing).
__launch_bounds__(256, 1)
__global__ void c1f2_k(const _Float16* __restrict__ fhf, const _Float16* __restrict__ fhw,
                       const _Float16* __restrict__ wfr, const float* __restrict__ b1,
                       const _Float16* __restrict__ w2a, const float* __restrict__ b2,
                       const _Float16* __restrict__ coefa, const float* __restrict__ bn,
                       _Float16* __restrict__ uH) {
    __shared__ alignas(16) char SMEM[32256];
    _Float16* TILEa = (_Float16*)SMEM;             // [2][180*40] = 28800 B (conv phase)
    _Float16* tL    = (_Float16*)SMEM;             // [128][68]  = 17408 B (transition)
    _Float16* PT    = (_Float16*)SMEM;             // [180][24]  =  8640 B (Phase B, over tL)
    _Float16* BSH   = (_Float16*)(SMEM + 17408);   // [128][58]  = 14848 B

    const int tid = threadIdx.x;
    const int lane = tid & 63, wv = tid >> 6;
    const int l15 = lane & 15, l4 = lane >> 4;
    const int x0 = blockIdx.x * 16, y0 = blockIdx.y * 8;
    const int nb = blockIdx.z;

    // ================= Phase C: conv1 (v6b) =================
    f32x4 cacc[8];
    #pragma unroll
    for (int nf = 0; nf < 8; ++nf)
        cacc[nf] = (f32x4){0.f, 0.f, 0.f, 0.f};

    half8v sv[3];
    auto issue = [&](int cc) {
        const _Float16* tens = (cc < 2) ? fhf : fhw;
        const int choff = (cc & 1) * 32;
        const _Float16* base = tens + (size_t)nb * HWSZ * 64;
        #pragma unroll
        for (int it = 0; it < 3; ++it) {
            int task = tid + it*256;
            sv[it] = h8zero();
            if (it < 2 || task < 720) {
                int pos = task >> 2, hh = task & 3;
                int py = pos / 18, px = pos - py*18;
                int gy = y0 - 1 + py, gx = x0 - 1 + px;
                bool ok = (gy >= 0) & (gy < HH) & (gx >= 0) & (gx < WW);
                if (ok) sv[it] = *(const half8v*)&base[((size_t)(gy*WW + gx))*64 + choff + hh*8];
            }
        }
    };
    auto commit = [&](int buf) {
        #pragma unroll
        for (int it = 0; it < 3; ++it) {
            int task = tid + it*256;
            if (it < 2 || task < 720) {
                int pos = task >> 2, hh = task & 3;
                *(half8v*)&TILEa[buf*7200 + pos*40 + hh*8] = sv[it];
            }
        }
    };

    half8v Wf[2];
    auto loadW = [&](int g, int b) {
        Wf[b] = *(const half8v*)(wfr + (size_t)(g*4 + wv)*512 + lane*8);
    };

    issue(0);
    commit(0);
    loadW(0, 0);
    __syncthreads();

    #pragma unroll
    for (int cc = 0; cc < 4; ++cc) {
        if (cc + 1 < 4) issue(cc + 1);
        const _Float16* Tc = &TILEa[(cc & 1)*7200];
        #pragma unroll
        for (int t = 0; t < 9; ++t) {
            const int g = cc*9 + t;
            const int b = g & 1;
            if (g + 1 < 36) loadW(g + 1, b ^ 1);
            const int ky = t / 3, kx = t - ky*3;
            #pragma unroll
            for (int nf = 0; nf < 8; ++nf) {
                int pos = (nf + ky)*18 + l15 + kx;
                half8v Ph = *(const half8v*)&Tc[pos*40 + l4*8];
                cacc[nf] = __builtin_amdgcn_mfma_f32_16x16x32_f16(Wf[b], Ph, cacc[nf], 0, 0, 0);
            }
        }
        if (cc + 1 < 4) {
            commit((cc + 1) & 1);
            __syncthreads();
        }
    }

    // ============== Transition: t -> tL (bias+ReLU, fp16) ==============
    __syncthreads();
    float bch[4];
    #pragma unroll
    for (int i = 0; i < 4; ++i) bch[i] = b1[wv*16 + l4*4 + i];
    #pragma unroll
    for (int nf = 0; nf < 8; ++nf) {
        half4v hv;
        #pragma unroll
        for (int i = 0; i < 4; ++i)
            hv[i] = (_Float16)fmaxf(cacc[nf][i] + bch[i], 0.f);
        *(half4v*)&tL[(nf*16 + l15)*68 + wv*16 + l4*4] = hv;
    }
    __syncthreads();

    // ================= Phase A: bases = w2 @ t =================
    half8v w2f[2][4];
    #pragma unroll
    for (int kc = 0; kc < 2; ++kc)
        #pragma unroll
        for (int mf = 0; mf < 4; ++mf)
            w2f[kc][mf] = *(const half8v*)(w2a + (size_t)((kc*4 + mf)*64 + lane)*8);

    f32x4 b2v[4];
    #pragma unroll
    for (int mf = 0; mf < 4; ++mf)
        #pragma unroll
        for (int i = 0; i < 4; ++i) {
            int row = mf*16 + l4*4 + i;
            b2v[mf][i] = (row < 54) ? b2[row] : 0.f;
        }

    int s_pos[2], s_gy[2], s_gx[2], s_oct[2];
    bool s_ok[2], s_act[2];
    #pragma unroll
    for (int it = 0; it < 2; ++it) {
        int task = tid + it*256;
        s_act[it] = (task < 360);
        int pos = task >> 1, oct = task & 1;
        int py = pos / 18, pxx = pos - py*18;
        int gy = y0 - 1 + py, gx = x0 - 1 + pxx;
        s_pos[it] = pos; s_oct[it] = oct;
        s_gy[it] = gy; s_gx[it] = gx;
        s_ok[it] = (gy >= 0) & (gy < HH) & (gx >= 0) & (gx < WW) & s_act[it];
    }
    const _Float16* fbase = fhf + (size_t)nb * HWSZ * 64;
    half8v sv0 = h8zero(), sv1 = h8zero();
    if (s_ok[0]) sv0 = *(const half8v*)&fbase[((size_t)(s_gy[0]*WW + s_gx[0]))*64 + s_oct[0]*8];
    if (s_ok[1]) sv1 = *(const half8v*)&fbase[((size_t)(s_gy[1]*WW + s_gx[1]))*64 + s_oct[1]*8];

    #pragma unroll
    for (int nf = 0; nf < 2; ++nf) {
        int r = wv*2 + nf;
        int px = r*16 + l15;
        half8v tf0 = *(const half8v*)&tL[px*68 + l4*8];
        half8v tf1 = *(const half8v*)&tL[px*68 + 32 + l4*8];
        #pragma unroll
        for (int mf = 0; mf < 4; ++mf) {
            f32x4 ab = (f32x4){0.f, 0.f, 0.f, 0.f};
            ab = __builtin_amdgcn_mfma_f32_16x16x32_f16(w2f[0][mf], tf0, ab, 0, 0, 0);
            ab = __builtin_amdgcn_mfma_f32_16x16x32_f16(w2f[1][mf], tf1, ab, 0, 0, 0);
            #pragma unroll
            for (int i = 0; i < 4; ++i) {
                int jb = mf*16 + l4*4 + i;
                if (jb < 54) {          // pad rows 54,55 SKIPPED (R23 aliasing bug)
                    int m = jb / 9;
                    int tap = jb - m*9;
                    BSH[px*58 + tap*6 + (m & 1)*3 + (m >> 1)] = (_Float16)(ab[i] + b2v[mf][i]);
                }
            }
        }
    }

    __syncthreads();                 // all tL reads done (PT overlays tL)

    const int m0 = l4 >> 1;
    const int c08 = (l4 & 1) * 8;
    #pragma unroll
    for (int it = 0; it < 2; ++it) {
        if (s_act[it])
            *(half8v*)&PT[s_pos[it]*24 + s_oct[it]*8] = (it ? sv1 : sv0);
    }
    __syncthreads();

    // ================= Phase B: einsum + coef MFMA =================
    f32x4 acc[4][2];
    #pragma unroll
    for (int m = 0; m < 4; ++m)
        #pragma unroll
        for (int nf = 0; nf < 2; ++nf)
            acc[m][nf] = (f32x4){0.f, 0.f, 0.f, 0.f};

    #pragma unroll 1
    for (int cg = 0; cg < 4; ++cg) {
        half8v nv0 = h8zero(), nv1 = h8zero();
        if (cg < 3) {
            int chb = (cg + 1)*16;
            if (s_ok[0]) nv0 = *(const half8v*)&fbase[((size_t)(s_gy[0]*WW + s_gx[0]))*64 + chb + s_oct[0]*8];
            if (s_ok[1]) nv1 = *(const half8v*)&fbase[((size_t)(s_gy[1]*WW + s_gx[1]))*64 + chb + s_oct[1]*8];
        }

        #pragma unroll
        for (int nf = 0; nf < 2; ++nf) {
            int r = wv*2 + nf;
            int px = r*16 + l15;
            half2v s2[3][4];
            #pragma unroll
            for (int ch = 0; ch < 3; ++ch)
                #pragma unroll
                for (int q = 0; q < 4; ++q)
                    s2[ch][q] = (half2v){(_Float16)0.f, (_Float16)0.f};

            #pragma unroll
            for (int tap = 0; tap < 9; ++tap) {
                int ky = tap / 3, kx = tap - ky*3;
                int pos = (r + ky)*18 + l15 + kx;
                half8v pt = *(const half8v*)&PT[pos*24 + c08];
                const _Float16* bvp = &BSH[px*58 + tap*6 + m0*3];
                _Float16 bva = bvp[0], bvb = bvp[1], bvc = bvp[2];
                half2v b0 = (half2v){bva, bva};
                half2v b1h = (half2v){bvb, bvb};
                half2v bx = (half2v){bvc, bvc};
                #pragma unroll
                for (int q = 0; q < 4; ++q) {
                    half2v pq = (half2v){pt[2*q], pt[2*q + 1]};
                    s2[0][q] = pq * b0 + s2[0][q];
                    s2[1][q] = pq * b1h + s2[1][q];
                    s2[2][q] = pq * bx + s2[2][q];
                }
            }
            half8v B0, B1, B2;
            #pragma unroll
            for (int q = 0; q < 4; ++q) {
                B0[2*q] = s2[0][q][0]; B0[2*q+1] = s2[0][q][1];
                B1[2*q] = s2[1][q][0]; B1[2*q+1] = s2[1][q][1];
                B2[2*q] = s2[2][q][0]; B2[2*q+1] = s2[2][q][1];
            }
            #pragma unroll
            for (int hf = 0; hf < 2; ++hf) {
                half8v CAh[3][2];
                #pragma unroll
                for (int ch = 0; ch < 3; ++ch)
                    #pragma unroll
                    for (int o = 0; o < 2; ++o)
                        CAh[ch][o] = *(const half8v*)(coefa +
                            (size_t)(((cg*3 + ch)*4 + hf*2 + o)*64 + lane)*8);
                #pragma unroll
                for (int o = 0; o < 2; ++o) {
                    int oc = hf*2 + o;
                    acc[oc][nf] = __builtin_amdgcn_mfma_f32_16x16x32_f16(CAh[0][o], B0, acc[oc][nf], 0, 0, 0);
                    acc[oc][nf] = __builtin_amdgcn_mfma_f32_16x16x32_f16(CAh[1][o], B1, acc[oc][nf], 0, 0, 0);
                    acc[oc][nf] = __builtin_amdgcn_mfma_f32_16x16x32_f16(CAh[2][o], B2, acc[oc][nf], 0, 0, 0);
                }
            }
        }

        if (cg < 3) {
            __syncthreads();
            #pragma unroll
            for (int it = 0; it < 2; ++it) {
                if (s_act[it])
                    *(half8v*)&PT[s_pos[it]*24 + s_oct[it]*8] = (it ? nv1 : nv0);
            }
            __syncthreads();
        }
    }

    // epilogue: BN(+coef_bias)+ReLU -> u
    #pragma unroll
    for (int nf = 0; nf < 2; ++nf) {
        int y = y0 + wv*2 + nf, x = x0 + l15;
        _Float16* up = uH + ((size_t)nb*HWSZ + y*WW + x) * 64;
        #pragma unroll
        for (int ocf = 0; ocf < 4; ++ocf) {
            half4v hv;
            #pragma unroll
            for (int i = 0; i < 4; ++i) {
                int co = ocf*16 + l4*4 + i;
                hv[i] = (_Float16)fmaxf(acc[ocf][nf][i]*bn[co] + bn[64 + co], 0.f);
            }
            *(half4v*)&up[ocf*16 + l4*4] = hv;
        }
    }
}

// ---------------- MFMA conv 3x3 v6b (conv1-fallback and conv3) ----------------
template<int CHUNKS, bool HAS_SCALE>
__launch_bounds__(256, 1)
__global__ void convmfma_k(const _Float16* __restrict__ in0, const _Float16* __restrict__ in1,
                           const _Float16* __restrict__ wfr,
                           const float* __restrict__ epiA, const float* __restrict__ epiB,
                           float* __restrict__ outF, _Float16* __restrict__ outH) {
    __shared__ alignas(16) _Float16 TILE[2][180*40];
    const int tid = threadIdx.x;
    const int lane = tid & 63, wv = tid >> 6;
    const int l15 = lane & 15, l4 = lane >> 4;
    const int x0 = blockIdx.x * 16, y0 = blockIdx.y * 8;
    const int nb = blockIdx.z;
    const int NT = CHUNKS * 9;

    f32x4 acc[8];
    #pragma unroll
    for (int nf = 0; nf < 8; ++nf)
        acc[nf] = (f32x4){0.f, 0.f, 0.f, 0.f};

    half8v sv[3];
    auto issue = [&](int cc) {
        const _Float16* tens = (cc < 2) ? in0 : in1;
        const int choff = (cc & 1) * 32;
        const _Float16* base = tens + (size_t)nb * HWSZ * 64;
        #pragma unroll
        for (int it = 0; it < 3; ++it) {
            int task = tid + it*256;
            sv[it] = h8zero();
            if (it < 2 || task < 720) {
                int pos = task >> 2, hh = task & 3;
                int py = pos / 18, px = pos - py*18;
                int gy = y0 - 1 + py, gx = x0 - 1 + px;
                bool ok = (gy >= 0) & (gy < HH) & (gx >= 0) & (gx < WW);
                if (ok) sv[it] = *(const half8v*)&base[((size_t)(gy*WW + gx))*64 + choff + hh*8];
            }
        }
    };
    auto commit = [&](int buf) {
        #pragma unroll
        for (int it = 0; it < 3; ++it) {
            int task = tid + it*256;
            if (it < 2 || task < 720) {
                int pos = task >> 2, hh = task & 3;
                *(half8v*)&TILE[buf][pos*40 + hh*8] = sv[it];
            }
        }
    };

    half8v Wf[2];
    auto loadW = [&](int g, int b) {
        Wf[b] = *(const half8v*)(wfr + (size_t)(g*4 + wv)*512 + lane*8);
    };

    issue(0);
    commit(0);
    loadW(0, 0);
    __syncthreads();

    #pragma unroll
    for (int cc = 0; cc < CHUNKS; ++cc) {
        if (cc + 1 < CHUNKS) issue(cc + 1);
        const _Float16* Tc = &TILE[cc & 1][0];
        #pragma unroll
        for (int t = 0; t < 9; ++t) {
            const int g = cc*9 + t;
            const int b = g & 1;
            if (g + 1 < NT) loadW(g + 1, b ^ 1);
            const int ky = t / 3, kx = t - ky*3;
            #pragma unroll
            for (int nf = 0; nf < 8; ++nf) {
                int pos = (nf + ky)*18 + l15 + kx;
                half8v Ph = *(const half8v*)&Tc[pos*40 + l4*8];
                acc[nf] = __builtin_amdgcn_mfma_f32_16x16x32_f16(Wf[b], Ph, acc[nf], 0, 0, 0);
            }
        }
        if (cc + 1 < CHUNKS) {
            commit((cc + 1) & 1);
            __syncthreads();
        }
    }

    if (HAS_SCALE) {
        #pragma unroll
        for (int i = 0; i < 4; ++i) {
            int co = wv*16 + l4*4 + i;
            float sc = epiA[co], ofs = epiB[co];
            float* op = outF + (size_t)(nb*64 + co) * HWSZ;
            #pragma unroll
            for (int nf = 0; nf < 8; ++nf) {
                int y = y0 + nf, x = x0 + l15;
                op[y*WW + x] = fmaxf(acc[nf][i]*sc + ofs, 0.f);
            }
        }
    } else {
        #pragma unroll
        for (int nf = 0; nf < 8; ++nf) {
            int y = y0 + nf, x = x0 + l15;
            _Float16* op = outH + ((size_t)nb*HWSZ + y*WW + x) * 64;
            half4v hv;
            #pragma unroll
            for (int i = 0; i < 4; ++i) {
                float v = acc[nf][i] + epiA[wv*16 + l4*4 + i];
                hv[i] = (_Float16)fmaxf(v, 0.f);
            }
            *(half4v*)&op[wv*16 + l4*4] = hv;
        }
    }
}

// ---------------- standalone fuse2 (fallback path; R20 v10) ----------------
__launch_bounds__(256, 1)
__global__ void fuse2_k(const _Float16* __restrict__ fhf, const _Float16* __restrict__ tH,
                        const _Float16* __restrict__ w2a,
                        const float* __restrict__ b2,
                        const _Float16* __restrict__ coefa,
                        const float* __restrict__ bn,
                        _Float16* __restrict__ uH) {
    __shared__ alignas(16) _Float16 BSH[128*72];
    __shared__ alignas(16) _Float16 PT[180*24];
    const int tid = threadIdx.x;
    const int lane = tid & 63, wv = tid >> 6;
    const int l15 = lane & 15, l4 = lane >> 4;
    const int x0 = blockIdx.x*16, y0 = blockIdx.y*8;
    const int nb = blockIdx.z;

    int s_pos[2], s_gy[2], s_gx[2], s_oct[2];
    bool s_ok[2], s_act[2];
    #pragma unroll
    for (int it = 0; it < 2; ++it) {
        int task = tid + it*256;
        s_act[it] = (task < 360);
        int pos = task >> 1, oct = task & 1;
        int py = pos / 18, pxx = pos - py*18;
        int gy = y0 - 1 + py, gx = x0 - 1 + pxx;
        s_pos[it] = pos; s_oct[it] = oct;
        s_gy[it] = gy; s_gx[it] = gx;
        s_ok[it] = (gy >= 0) & (gy < HH) & (gx >= 0) & (gx < WW) & s_act[it];
    }
    const _Float16* fbase = fhf + (size_t)nb * HWSZ * 64;

    half8v sv0 = h8zero(), sv1 = h8zero();
    if (s_ok[0]) sv0 = *(const half8v*)&fbase[((size_t)(s_gy[0]*WW + s_gx[0]))*64 + s_oct[0]*8];
    if (s_ok[1]) sv1 = *(const half8v*)&fbase[((size_t)(s_gy[1]*WW + s_gx[1]))*64 + s_oct[1]*8];

    half8v w2f[2][4];
    #pragma unroll
    for (int kc = 0; kc < 2; ++kc)
        #pragma unroll
        for (int mf = 0; mf < 4; ++mf)
            w2f[kc][mf] = *(const half8v*)(w2a + (size_t)((kc*4 + mf)*64 + lane)*8);

    f32x4 b2v[4];
    #pragma unroll
    for (int mf = 0; mf < 4; ++mf)
        #pragma unroll
        for (int i = 0; i < 4; ++i) {
            int row = mf*16 + l4*4 + i;
            b2v[mf][i] = (row < 54) ? b2[row] : 0.f;
        }

    #pragma unroll
    for (int nf = 0; nf < 2; ++nf) {
        int r = wv*2 + nf;
        int y = y0 + r, x = x0 + l15;
        const _Float16* tp = tH + ((size_t)nb*HWSZ + y*WW + x) * 64;
        half8v tf0 = *(const half8v*)&tp[l4*8];
        half8v tf1 = *(const half8v*)&tp[32 + l4*8];
        int px = r*16 + l15;
        #pragma unroll
        for (int mf = 0; mf < 4; ++mf) {
            f32x4 ab = (f32x4){0.f, 0.f, 0.f, 0.f};
            ab = __builtin_amdgcn_mfma_f32_16x16x32_f16(w2f[0][mf], tf0, ab, 0, 0, 0);
            ab = __builtin_amdgcn_mfma_f32_16x16x32_f16(w2f[1][mf], tf1, ab, 0, 0, 0);
            if (mf < 3 || l4 < 2) {
                #pragma unroll
                for (int i = 0; i < 4; ++i) {
                    int jb = mf*16 + l4*4 + i;
                    int m = jb / 9;
                    int tap = jb - m*9;
                    BSH[px*72 + tap*8 + (m & 1)*4 + (m >> 1)] = (_Float16)(ab[i] + b2v[mf][i]);
                }
            }
        }
    }

    const int m0 = l4 >> 1;
    const int c08 = (l4 & 1) * 8;
    #pragma unroll
    for (int it = 0; it < 2; ++it) {
        if (s_act[it])
            *(half8v*)&PT[s_pos[it]*24 + s_oct[it]*8] = (it ? sv1 : sv0);
    }
    __syncthreads();

    f32x4 acc[4][2];
    #pragma unroll
    for (int m = 0; m < 4; ++m)
        #pragma unroll
        for (int nf = 0; nf < 2; ++nf)
            acc[m][nf] = (f32x4){0.f, 0.f, 0.f, 0.f};

    #pragma unroll 1
    for (int cg = 0; cg < 4; ++cg) {
        half8v nv0 = h8zero(), nv1 = h8zero();
        if (cg < 3) {
            int chb = (cg + 1)*16;
            if (s_ok[0]) nv0 = *(const half8v*)&fbase[((size_t)(s_gy[0]*WW + s_gx[0]))*64 + chb + s_oct[0]*8];
            if (s_ok[1]) nv1 = *(const half8v*)&fbase[((size_t)(s_gy[1]*WW + s_gx[1]))*64 + chb + s_oct[1]*8];
        }

        #pragma unroll
        for (int nf = 0; nf < 2; ++nf) {
            int r = wv*2 + nf;
            int px = r*16 + l15;
            half2v s2[3][4];
            #pragma unroll
            for (int ch = 0; ch < 3; ++ch)
                #pragma unroll
                for (int q = 0; q < 4; ++q)
                    s2[ch][q] = (half2v){(_Float16)0.f, (_Float16)0.f};

            #pragma unroll
            for (int tap = 0; tap < 9; ++tap) {
                int ky = tap / 3, kx = tap - ky*3;
                int pos = (r + ky)*18 + l15 + kx;
                half8v pt = *(const half8v*)&PT[pos*24 + c08];
                half4v bv = *(const half4v*)&BSH[px*72 + tap*8 + m0*4];
                half2v b0 = (half2v){bv[0], bv[0]};
                half2v b1 = (half2v){bv[1], bv[1]};
                half2v bx = (half2v){bv[2], bv[2]};
                #pragma unroll
                for (int q = 0; q < 4; ++q) {
                    half2v pq = (half2v){pt[2*q], pt[2*q + 1]};
                    s2[0][q] = pq * b0 + s2[0][q];
                    s2[1][q] = pq * b1 + s2[1][q];
                    s2[2][q] = pq * bx + s2[2][q];
                }
            }
            half8v B0, B1, B2;
            #pragma unroll
            for (int q = 0; q < 4; ++q) {
                B0[2*q] = s2[0][q][0]; B0[2*q+1] = s2[0][q][1];
                B1[2*q] = s2[1][q][0]; B1[2*q+1] = s2[1][q][1];
                B2[2*q] = s2[2][q][0]; B2[2*q+1] = s2[2][q][1];
            }
            #pragma unroll
            for (int hf = 0; hf < 2; ++hf) {
                half8v CAh[3][2];
                #pragma unroll
                for (int ch = 0; ch < 3; ++ch)
                    #pragma unroll
                    for (int o = 0; o < 2; ++o)
                        CAh[ch][o] = *(const half8v*)(coefa +
                            (size_t)(((cg*3 + ch)*4 + hf*2 + o)*64 + lane)*8);
                #pragma unroll
                for (int o = 0; o < 2; ++o) {
                    int oc = hf*2 + o;
                    acc[oc][nf] = __builtin_amdgcn_mfma_f32_16x16x32_f16(CAh[0][o], B0, acc[oc][nf], 0, 0, 0);
                    acc[oc][nf] = __builtin_amdgcn_mfma_f32_16x16x32_f16(CAh[1][o], B1, acc[oc][nf], 0, 0, 0);
                    acc[oc][nf] = __builtin_amdgcn_mfma_f32_16x16x32_f16(CAh[2][o], B2, acc[oc][nf], 0, 0, 0);
                }
            }
        }

        if (cg < 3) {
            __syncthreads();
            #pragma unroll
            for (int it = 0; it < 2; ++it) {
                if (s_act[it])
                    *(half8v*)&PT[s_pos[it]*24 + s_oct[it]*8] = (it ? nv1 : nv0);
            }
            __syncthreads();
        }
    }

    #pragma unroll
    for (int nf = 0; nf < 2; ++nf) {
        int y = y0 + wv*2 + nf, x = x0 + l15;
        _Float16* up = uH + ((size_t)nb*HWSZ + y*WW + x) * 64;
        #pragma unroll
        for (int ocf = 0; ocf < 4; ++ocf) {
            half4v hv;
            #pragma unroll
            for (int i = 0; i < 4; ++i) {
                int co = ocf*16 + l4*4 + i;
                hv[i] = (_Float16)fmaxf(acc[ocf][nf][i]*bn[co] + bn[64 + co], 0.f);
            }
            *(half4v*)&up[ocf*16 + l4*4] = hv;
        }
    }
}

extern "C" void kernel_launch(void* const* d_in, const int* in_sizes, int n_in,
                              void* d_out, int out_size, void* d_ws, size_t ws_size,
                              hipStream_t stream) {
    const float* feat      = (const float*)d_in[0];
    const float* wgt       = (const float*)d_in[1];
    const float* w1        = (const float*)d_in[2];
    const float* b1        = (const float*)d_in[3];
    const float* w2        = (const float*)d_in[4];
    const float* b2        = (const float*)d_in[5];
    const float* coef      = (const float*)d_in[6];
    const float* coef_bias = (const float*)d_in[7];
    const float* brg       = (const float*)d_in[8];
    const float* brb       = (const float*)d_in[9];
    const float* brm       = (const float*)d_in[10];
    const float* brv       = (const float*)d_in[11];
    const float* w3        = (const float*)d_in[12];
    const float* g3        = (const float*)d_in[13];
    const float* b3        = (const float*)d_in[14];
    const float* m3        = (const float*)d_in[15];
    const float* v3        = (const float*)d_in[16];

    float* out = (float*)d_out;
    _Float16* tH = (_Float16*)d_out;
    float* ws  = (float*)d_ws;
    _Float16* hw = (_Float16*)ws;
    _Float16* FHf = hw + OFF_FHF/2;
    _Float16* FHw = hw + OFF_FHW/2;

    nhwc_k<<<dim3(5, 240, 4), 256, 0, stream>>>(feat, wgt, FHf, FHw,
        w1, w3, w2, coef, coef_bias, brg, brb, brm, brv, g3, b3, m3, v3, ws);

    dim3 grid(WW/16, HH/8, NN);   // (20, 30, 2) = 1200 blocks

    if (ws_size >= (size_t)WS_FUSED) {
        // FUSED path: t stays in LDS; u -> disjoint OFF_U region
        _Float16* U = hw + OFF_U/2;
        c1f2_k<<<grid, 256, 0, stream>>>(FHf, FHw, hw + OFF_BW1/2, b1,
            hw + OFF_W2A/2, b2, hw + OFF_COEFA/2, ws + OFF_BN/4, U);
        convmfma_k<2, true><<<grid, 256, 0, stream>>>(
            U, U, hw + OFF_BW3/2,
            ws + OFF_BN/4 + 128, ws + OFF_BN/4 + 192, out, nullptr);
    } else {
        // FALLBACK (R20, known-good): t -> d_out; u -> FHw
        convmfma_k<4, false><<<grid, 256, 0, stream>>>(
            FHf, FHw, hw + OFF_BW1/2, b1, b1, nullptr, tH);
        fuse2_k<<<grid, 256, 0, stream>>>(FHf, tH,
            hw + OFF_W2A/2, b2, hw + OFF_COEFA/2, ws + OFF_BN/4, FHw);
        convmfma_k<2, true><<<grid, 256, 0, stream>>>(
            FHw, FHw, hw + OFF_BW3/2,
            ws + OFF_BN/4 + 128, ws + OFF_BN/4 + 192, out, nullptr);
    }
}

// Round 25
// 99.703 us; speedup vs baseline: 1.0254x; 1.0254x over previous
//
#include <hip/hip_runtime.h>
#include <math.h>

#define HH 240
#define WW 320
#define HWSZ (240*320)
#define NN 2

// Workspace layout (bytes)
#define OFF_BW1   0          // conv1 fp16 frags: 147456
#define OFF_BW3   147456     // conv3 fp16 frags: 73728
#define OFF_W2A   221184     // bases-GEMM A frags: 8192
#define OFF_COEFA 229376     // coef-GEMM A frags: 49152
#define OFF_BN    278528     // [sbr(64), bbr2(64), s3(64), o3(64)] f32 = 1024
#define OFF_FHF   279552     // feat NHWC fp16: 19660800
#define OFF_FHW   19940352   // wgt NHWC fp16: 19660800
#define OFF_U     39601152   // u NHWC fp16 (fused path only): 19660800
#define WS_FUSED  (OFF_U + 19660800)   // 59,261,952 B

typedef __attribute__((ext_vector_type(8))) _Float16 half8v;
typedef __attribute__((ext_vector_type(4))) _Float16 half4v;
typedef __attribute__((ext_vector_type(2))) _Float16 half2v;
typedef __attribute__((ext_vector_type(4))) float f32x4;

__device__ __forceinline__ half8v h8zero() {
    half8v z;
    #pragma unroll
    for (int j = 0; j < 8; ++j) z[j] = (_Float16)0.f;
    return z;
}

// ---------------- prep work (device fn; side-duty inside nhwc_k) ----------------
__device__ void do_prep(int id, const float* __restrict__ w1, const float* __restrict__ w3,
                        const float* __restrict__ w2, const float* __restrict__ coef,
                        const float* __restrict__ coef_bias,
                        const float* __restrict__ brg, const float* __restrict__ brb,
                        const float* __restrict__ brm, const float* __restrict__ brv,
                        const float* __restrict__ g3, const float* __restrict__ b3,
                        const float* __restrict__ m3, const float* __restrict__ v3,
                        float* __restrict__ ws) {
    _Float16* hw = (_Float16*)ws;

    if (id < 9216) {    // conv1 frags: frag = g*4 + m, g = cc*9 + t
        int l = id & 63; int f = id >> 6;
        int m = f & 3;   int g = f >> 2;
        int t = g % 9, cc = g / 9;
        _Float16* dst = hw + OFF_BW1/2 + (size_t)(g*4 + m)*512 + l*8;
        #pragma unroll
        for (int j = 0; j < 8; ++j) {
            int ci = cc*32 + (l>>4)*8 + j;
            int co = m*16 + (l&15);
            dst[j] = (_Float16)w1[(co*128 + ci)*9 + t];
        }
        return;
    }
    id -= 9216;
    if (id < 4608) {    // conv3 frags
        int l = id & 63; int f = id >> 6;
        int m = f & 3;   int g = f >> 2;
        int t = g % 9, cc = g / 9;
        _Float16* dst = hw + OFF_BW3/2 + (size_t)(g*4 + m)*512 + l*8;
        #pragma unroll
        for (int j = 0; j < 8; ++j) {
            int ci = cc*32 + (l>>4)*8 + j;
            int co = m*16 + (l&15);
            dst[j] = (_Float16)w3[(co*64 + ci)*9 + t];
        }
        return;
    }
    id -= 4608;
    if (id < 512) {     // W2A: A[row=j 54pad64][k=c 64]
        int l = id & 63; int f = id >> 6;
        int mf = f & 3, kc = f >> 2;
        int row = mf*16 + (l & 15);
        _Float16* dst = hw + OFF_W2A/2 + (size_t)((kc*4 + mf)*64 + l)*8;
        #pragma unroll
        for (int j = 0; j < 8; ++j) {
            int k = kc*32 + (l>>4)*8 + j;
            dst[j] = (row < 54) ? (_Float16)w2[row*64 + k] : (_Float16)0.f;
        }
        return;
    }
    id -= 512;
    if (id < 3072) {    // COEFA: k-order cg*96 + m_local*16 + c_local
        int l = id & 63; int f = id >> 6;
        int ocf = f & 3; int g2 = f >> 2;
        int ch = g2 % 3, cg = g2 / 3;
        int oc = ocf*16 + (l & 15);
        _Float16* dst = hw + OFF_COEFA/2 + (size_t)((g2*4 + ocf)*64 + l)*8;
        #pragma unroll
        for (int j = 0; j < 8; ++j) {
            int k32 = (l>>4)*8 + j;
            int m = ch*2 + (k32 >> 4);
            int c = cg*16 + (k32 & 15);
            dst[j] = (_Float16)coef[oc*384 + c*6 + m];
        }
        return;
    }
    id -= 3072;
    if (id < 64) {
        float s = brg[id] * rsqrtf(brv[id] + 1e-5f);
        ws[OFF_BN/4 + id]      = s;
        ws[OFF_BN/4 + 64 + id] = coef_bias[id]*s + brb[id] - brm[id]*s;
        return;
    }
    id -= 64;
    if (id < 64) {
        float s = g3[id] * rsqrtf(v3[id] + 1e-5f);
        ws[OFF_BN/4 + 128 + id] = s;
        ws[OFF_BN/4 + 192 + id] = b3[id] - m3[id]*s;
    }
}

// ---------------- NCHW f32 -> NHWC fp16 transpose + prep side-duty ----------------
__global__ void nhwc_k(const float* __restrict__ feat, const float* __restrict__ wgt,
                       _Float16* __restrict__ fhf, _Float16* __restrict__ fhw,
                       const float* __restrict__ w1, const float* __restrict__ w3,
                       const float* __restrict__ w2, const float* __restrict__ coef,
                       const float* __restrict__ coef_bias,
                       const float* __restrict__ brg, const float* __restrict__ brb,
                       const float* __restrict__ brm, const float* __restrict__ brv,
                       const float* __restrict__ g3, const float* __restrict__ b3,
                       const float* __restrict__ m3, const float* __restrict__ v3,
                       float* __restrict__ ws) {
    __shared__ float L[64][65];
    const int tid = threadIdx.x;

    const int bid = blockIdx.y * 5 + blockIdx.x;
    if (blockIdx.z == 0 && bid < 69)
        do_prep(bid*256 + tid, w1, w3, w2, coef, coef_bias,
                brg, brb, brm, brv, g3, b3, m3, v3, ws);

    const int xb = blockIdx.x * 64, y = blockIdx.y;
    const int n = blockIdx.z >> 1, w = blockIdx.z & 1;
    const float* src = (w ? wgt : feat) + (size_t)n*64*HWSZ + y*WW + xb;
    _Float16* dst = (w ? fhw : fhf) + ((size_t)n*HWSZ + y*WW + xb) * 64;
    const int lx = tid & 63, c4 = tid >> 6;
    #pragma unroll
    for (int k = 0; k < 16; ++k) {
        int c = c4*16 + k;
        L[c][lx] = src[(size_t)c*HWSZ + lx];
    }
    __syncthreads();
    const int x = tid >> 3, c0 = (tid & 7) * 8;
    #pragma unroll
    for (int h = 0; h < 2; ++h) {
        int xx = x + h*32;
        half8v v;
        #pragma unroll
        for (int j = 0; j < 8; ++j) v[j] = (_Float16)L[c0 + j][xx];
        *(half8v*)&dst[xx*64 + c0] = v;
    }
}

// ---------------- FUSED conv1 + fuse2: t stays in LDS (R22 best-measured) ----------------
__launch_bounds__(256, 1)
__global__ void c1f2_k(const _Float16* __restrict__ fhf, const _Float16* __restrict__ fhw,
                       const _Float16* __restrict__ wfr, const float* __restrict__ b1,
                       const _Float16* __restrict__ w2a, const float* __restrict__ b2,
                       const _Float16* __restrict__ coefa, const float* __restrict__ bn,
                       _Float16* __restrict__ uH) {
    __shared__ alignas(16) char SMEM[35840];
    _Float16* TILEa = (_Float16*)SMEM;             // [2][180*40] = 28800 B (conv phase)
    _Float16* tL    = (_Float16*)SMEM;             // [128][68]  = 17408 B (transition)
    _Float16* PT    = (_Float16*)SMEM;             // [180][24]  =  8640 B (Phase B, over tL)
    _Float16* BSH   = (_Float16*)(SMEM + 17408);   // [128][72]  = 18432 B

    const int tid = threadIdx.x;
    const int lane = tid & 63, wv = tid >> 6;
    const int l15 = lane & 15, l4 = lane >> 4;
    const int x0 = blockIdx.x * 16, y0 = blockIdx.y * 8;
    const int nb = blockIdx.z;

    // ================= Phase C: conv1 (v6b) =================
    f32x4 cacc[8];
    #pragma unroll
    for (int nf = 0; nf < 8; ++nf)
        cacc[nf] = (f32x4){0.f, 0.f, 0.f, 0.f};

    half8v sv[3];
    auto issue = [&](int cc) {
        const _Float16* tens = (cc < 2) ? fhf : fhw;
        const int choff = (cc & 1) * 32;
        const _Float16* base = tens + (size_t)nb * HWSZ * 64;
        #pragma unroll
        for (int it = 0; it < 3; ++it) {
            int task = tid + it*256;
            sv[it] = h8zero();
            if (it < 2 || task < 720) {
                int pos = task >> 2, hh = task & 3;
                int py = pos / 18, px = pos - py*18;
                int gy = y0 - 1 + py, gx = x0 - 1 + px;
                bool ok = (gy >= 0) & (gy < HH) & (gx >= 0) & (gx < WW);
                if (ok) sv[it] = *(const half8v*)&base[((size_t)(gy*WW + gx))*64 + choff + hh*8];
            }
        }
    };
    auto commit = [&](int buf) {
        #pragma unroll
        for (int it = 0; it < 3; ++it) {
            int task = tid + it*256;
            if (it < 2 || task < 720) {
                int pos = task >> 2, hh = task & 3;
                *(half8v*)&TILEa[buf*7200 + pos*40 + hh*8] = sv[it];
            }
        }
    };

    half8v Wf[2];
    auto loadW = [&](int g, int b) {
        Wf[b] = *(const half8v*)(wfr + (size_t)(g*4 + wv)*512 + lane*8);
    };

    issue(0);
    commit(0);
    loadW(0, 0);
    __syncthreads();

    #pragma unroll
    for (int cc = 0; cc < 4; ++cc) {
        if (cc + 1 < 4) issue(cc + 1);
        const _Float16* Tc = &TILEa[(cc & 1)*7200];
        #pragma unroll
        for (int t = 0; t < 9; ++t) {
            const int g = cc*9 + t;
            const int b = g & 1;
            if (g + 1 < 36) loadW(g + 1, b ^ 1);
            const int ky = t / 3, kx = t - ky*3;
            #pragma unroll
            for (int nf = 0; nf < 8; ++nf) {
                int pos = (nf + ky)*18 + l15 + kx;
                half8v Ph = *(const half8v*)&Tc[pos*40 + l4*8];
                cacc[nf] = __builtin_amdgcn_mfma_f32_16x16x32_f16(Wf[b], Ph, cacc[nf], 0, 0, 0);
            }
        }
        if (cc + 1 < 4) {
            commit((cc + 1) & 1);
            __syncthreads();
        }
    }

    // ============== Transition: t -> tL (bias+ReLU, fp16) ==============
    __syncthreads();
    float bch[4];
    #pragma unroll
    for (int i = 0; i < 4; ++i) bch[i] = b1[wv*16 + l4*4 + i];
    #pragma unroll
    for (int nf = 0; nf < 8; ++nf) {
        half4v hv;
        #pragma unroll
        for (int i = 0; i < 4; ++i)
            hv[i] = (_Float16)fmaxf(cacc[nf][i] + bch[i], 0.f);
        *(half4v*)&tL[(nf*16 + l15)*68 + wv*16 + l4*4] = hv;
    }
    __syncthreads();

    // ================= Phase A: bases = w2 @ t =================
    half8v w2f[2][4];
    #pragma unroll
    for (int kc = 0; kc < 2; ++kc)
        #pragma unroll
        for (int mf = 0; mf < 4; ++mf)
            w2f[kc][mf] = *(const half8v*)(w2a + (size_t)((kc*4 + mf)*64 + lane)*8);

    f32x4 b2v[4];
    #pragma unroll
    for (int mf = 0; mf < 4; ++mf)
        #pragma unroll
        for (int i = 0; i < 4; ++i) {
            int row = mf*16 + l4*4 + i;
            b2v[mf][i] = (row < 54) ? b2[row] : 0.f;
        }

    int s_pos[2], s_gy[2], s_gx[2], s_oct[2];
    bool s_ok[2], s_act[2];
    #pragma unroll
    for (int it = 0; it < 2; ++it) {
        int task = tid + it*256;
        s_act[it] = (task < 360);
        int pos = task >> 1, oct = task & 1;
        int py = pos / 18, pxx = pos - py*18;
        int gy = y0 - 1 + py, gx = x0 - 1 + pxx;
        s_pos[it] = pos; s_oct[it] = oct;
        s_gy[it] = gy; s_gx[it] = gx;
        s_ok[it] = (gy >= 0) & (gy < HH) & (gx >= 0) & (gx < WW) & s_act[it];
    }
    const _Float16* fbase = fhf + (size_t)nb * HWSZ * 64;
    half8v sv0 = h8zero(), sv1 = h8zero();
    if (s_ok[0]) sv0 = *(const half8v*)&fbase[((size_t)(s_gy[0]*WW + s_gx[0]))*64 + s_oct[0]*8];
    if (s_ok[1]) sv1 = *(const half8v*)&fbase[((size_t)(s_gy[1]*WW + s_gx[1]))*64 + s_oct[1]*8];

    #pragma unroll
    for (int nf = 0; nf < 2; ++nf) {
        int r = wv*2 + nf;
        int px = r*16 + l15;
        half8v tf0 = *(const half8v*)&tL[px*68 + l4*8];
        half8v tf1 = *(const half8v*)&tL[px*68 + 32 + l4*8];
        #pragma unroll
        for (int mf = 0; mf < 4; ++mf) {
            f32x4 ab = (f32x4){0.f, 0.f, 0.f, 0.f};
            ab = __builtin_amdgcn_mfma_f32_16x16x32_f16(w2f[0][mf], tf0, ab, 0, 0, 0);
            ab = __builtin_amdgcn_mfma_f32_16x16x32_f16(w2f[1][mf], tf1, ab, 0, 0, 0);
            if (mf < 3 || l4 < 2) {
                #pragma unroll
                for (int i = 0; i < 4; ++i) {
                    int jb = mf*16 + l4*4 + i;
                    int m = jb / 9;
                    int tap = jb - m*9;
                    BSH[px*72 + tap*8 + (m & 1)*4 + (m >> 1)] = (_Float16)(ab[i] + b2v[mf][i]);
                }
            }
        }
    }

    __syncthreads();                 // all tL reads done (PT overlays tL)

    const int m0 = l4 >> 1;
    const int c08 = (l4 & 1) * 8;
    #pragma unroll
    for (int it = 0; it < 2; ++it) {
        if (s_act[it])
            *(half8v*)&PT[s_pos[it]*24 + s_oct[it]*8] = (it ? sv1 : sv0);
    }
    __syncthreads();

    // ================= Phase B: einsum + coef MFMA =================
    f32x4 acc[4][2];
    #pragma unroll
    for (int m = 0; m < 4; ++m)
        #pragma unroll
        for (int nf = 0; nf < 2; ++nf)
            acc[m][nf] = (f32x4){0.f, 0.f, 0.f, 0.f};

    #pragma unroll 1
    for (int cg = 0; cg < 4; ++cg) {
        half8v nv0 = h8zero(), nv1 = h8zero();
        if (cg < 3) {
            int chb = (cg + 1)*16;
            if (s_ok[0]) nv0 = *(const half8v*)&fbase[((size_t)(s_gy[0]*WW + s_gx[0]))*64 + chb + s_oct[0]*8];
            if (s_ok[1]) nv1 = *(const half8v*)&fbase[((size_t)(s_gy[1]*WW + s_gx[1]))*64 + chb + s_oct[1]*8];
        }

        #pragma unroll
        for (int nf = 0; nf < 2; ++nf) {
            int r = wv*2 + nf;
            int px = r*16 + l15;
            half2v s2[3][4];
            #pragma unroll
            for (int ch = 0; ch < 3; ++ch)
                #pragma unroll
                for (int q = 0; q < 4; ++q)
                    s2[ch][q] = (half2v){(_Float16)0.f, (_Float16)0.f};

            #pragma unroll
            for (int tap = 0; tap < 9; ++tap) {
                int ky = tap / 3, kx = tap - ky*3;
                int pos = (r + ky)*18 + l15 + kx;
                half8v pt = *(const half8v*)&PT[pos*24 + c08];
                half4v bv = *(const half4v*)&BSH[px*72 + tap*8 + m0*4];
                half2v b0 = (half2v){bv[0], bv[0]};
                half2v b1h = (half2v){bv[1], bv[1]};
                half2v bx = (half2v){bv[2], bv[2]};
                #pragma unroll
                for (int q = 0; q < 4; ++q) {
                    half2v pq = (half2v){pt[2*q], pt[2*q + 1]};
                    s2[0][q] = pq * b0 + s2[0][q];
                    s2[1][q] = pq * b1h + s2[1][q];
                    s2[2][q] = pq * bx + s2[2][q];
                }
            }
            half8v B0, B1, B2;
            #pragma unroll
            for (int q = 0; q < 4; ++q) {
                B0[2*q] = s2[0][q][0]; B0[2*q+1] = s2[0][q][1];
                B1[2*q] = s2[1][q][0]; B1[2*q+1] = s2[1][q][1];
                B2[2*q] = s2[2][q][0]; B2[2*q+1] = s2[2][q][1];
            }
            #pragma unroll
            for (int hf = 0; hf < 2; ++hf) {
                half8v CAh[3][2];
                #pragma unroll
                for (int ch = 0; ch < 3; ++ch)
                    #pragma unroll
                    for (int o = 0; o < 2; ++o)
                        CAh[ch][o] = *(const half8v*)(coefa +
                            (size_t)(((cg*3 + ch)*4 + hf*2 + o)*64 + lane)*8);
                #pragma unroll
                for (int o = 0; o < 2; ++o) {
                    int oc = hf*2 + o;
                    acc[oc][nf] = __builtin_amdgcn_mfma_f32_16x16x32_f16(CAh[0][o], B0, acc[oc][nf], 0, 0, 0);
                    acc[oc][nf] = __builtin_amdgcn_mfma_f32_16x16x32_f16(CAh[1][o], B1, acc[oc][nf], 0, 0, 0);
                    acc[oc][nf] = __builtin_amdgcn_mfma_f32_16x16x32_f16(CAh[2][o], B2, acc[oc][nf], 0, 0, 0);
                }
            }
        }

        if (cg < 3) {
            __syncthreads();
            #pragma unroll
            for (int it = 0; it < 2; ++it) {
                if (s_act[it])
                    *(half8v*)&PT[s_pos[it]*24 + s_oct[it]*8] = (it ? nv1 : nv0);
            }
            __syncthreads();
        }
    }

    // epilogue: BN(+coef_bias)+ReLU -> u (disjoint buffer)
    #pragma unroll
    for (int nf = 0; nf < 2; ++nf) {
        int y = y0 + wv*2 + nf, x = x0 + l15;
        _Float16* up = uH + ((size_t)nb*HWSZ + y*WW + x) * 64;
        #pragma unroll
        for (int ocf = 0; ocf < 4; ++ocf) {
            half4v hv;
            #pragma unroll
            for (int i = 0; i < 4; ++i) {
                int co = ocf*16 + l4*4 + i;
                hv[i] = (_Float16)fmaxf(acc[ocf][nf][i]*bn[co] + bn[64 + co], 0.f);
            }
            *(half4v*)&up[ocf*16 + l4*4] = hv;
        }
    }
}

// ---------------- MFMA conv 3x3 v6b (conv1-fallback and conv3) ----------------
template<int CHUNKS, bool HAS_SCALE>
__launch_bounds__(256, 1)
__global__ void convmfma_k(const _Float16* __restrict__ in0, const _Float16* __restrict__ in1,
                           const _Float16* __restrict__ wfr,
                           const float* __restrict__ epiA, const float* __restrict__ epiB,
                           float* __restrict__ outF, _Float16* __restrict__ outH) {
    __shared__ alignas(16) _Float16 TILE[2][180*40];
    const int tid = threadIdx.x;
    const int lane = tid & 63, wv = tid >> 6;
    const int l15 = lane & 15, l4 = lane >> 4;
    const int x0 = blockIdx.x * 16, y0 = blockIdx.y * 8;
    const int nb = blockIdx.z;
    const int NT = CHUNKS * 9;

    f32x4 acc[8];
    #pragma unroll
    for (int nf = 0; nf < 8; ++nf)
        acc[nf] = (f32x4){0.f, 0.f, 0.f, 0.f};

    half8v sv[3];
    auto issue = [&](int cc) {
        const _Float16* tens = (cc < 2) ? in0 : in1;
        const int choff = (cc & 1) * 32;
        const _Float16* base = tens + (size_t)nb * HWSZ * 64;
        #pragma unroll
        for (int it = 0; it < 3; ++it) {
            int task = tid + it*256;
            sv[it] = h8zero();
            if (it < 2 || task < 720) {
                int pos = task >> 2, hh = task & 3;
                int py = pos / 18, px = pos - py*18;
                int gy = y0 - 1 + py, gx = x0 - 1 + px;
                bool ok = (gy >= 0) & (gy < HH) & (gx >= 0) & (gx < WW);
                if (ok) sv[it] = *(const half8v*)&base[((size_t)(gy*WW + gx))*64 + choff + hh*8];
            }
        }
    };
    auto commit = [&](int buf) {
        #pragma unroll
        for (int it = 0; it < 3; ++it) {
            int task = tid + it*256;
            if (it < 2 || task < 720) {
                int pos = task >> 2, hh = task & 3;
                *(half8v*)&TILE[buf][pos*40 + hh*8] = sv[it];
            }
        }
    };

    half8v Wf[2];
    auto loadW = [&](int g, int b) {
        Wf[b] = *(const half8v*)(wfr + (size_t)(g*4 + wv)*512 + lane*8);
    };

    issue(0);
    commit(0);
    loadW(0, 0);
    __syncthreads();

    #pragma unroll
    for (int cc = 0; cc < CHUNKS; ++cc) {
        if (cc + 1 < CHUNKS) issue(cc + 1);
        const _Float16* Tc = &TILE[cc & 1][0];
        #pragma unroll
        for (int t = 0; t < 9; ++t) {
            const int g = cc*9 + t;
            const int b = g & 1;
            if (g + 1 < NT) loadW(g + 1, b ^ 1);
            const int ky = t / 3, kx = t - ky*3;
            #pragma unroll
            for (int nf = 0; nf < 8; ++nf) {
                int pos = (nf + ky)*18 + l15 + kx;
                half8v Ph = *(const half8v*)&Tc[pos*40 + l4*8];
                acc[nf] = __builtin_amdgcn_mfma_f32_16x16x32_f16(Wf[b], Ph, acc[nf], 0, 0, 0);
            }
        }
        if (cc + 1 < CHUNKS) {
            commit((cc + 1) & 1);
            __syncthreads();
        }
    }

    if (HAS_SCALE) {
        #pragma unroll
        for (int i = 0; i < 4; ++i) {
            int co = wv*16 + l4*4 + i;
            float sc = epiA[co], ofs = epiB[co];
            float* op = outF + (size_t)(nb*64 + co) * HWSZ;
            #pragma unroll
            for (int nf = 0; nf < 8; ++nf) {
                int y = y0 + nf, x = x0 + l15;
                op[y*WW + x] = fmaxf(acc[nf][i]*sc + ofs, 0.f);
            }
        }
    } else {
        #pragma unroll
        for (int nf = 0; nf < 8; ++nf) {
            int y = y0 + nf, x = x0 + l15;
            _Float16* op = outH + ((size_t)nb*HWSZ + y*WW + x) * 64;
            half4v hv;
            #pragma unroll
            for (int i = 0; i < 4; ++i) {
                float v = acc[nf][i] + epiA[wv*16 + l4*4 + i];
                hv[i] = (_Float16)fmaxf(v, 0.f);
            }
            *(half4v*)&op[wv*16 + l4*4] = hv;
        }
    }
}

// ---------------- standalone fuse2 (fallback path; R20 v10) ----------------
__launch_bounds__(256, 1)
__global__ void fuse2_k(const _Float16* __restrict__ fhf, const _Float16* __restrict__ tH,
                        const _Float16* __restrict__ w2a,
                        const float* __restrict__ b2,
                        const _Float16* __restrict__ coefa,
                        const float* __restrict__ bn,
                        _Float16* __restrict__ uH) {
    __shared__ alignas(16) _Float16 BSH[128*72];
    __shared__ alignas(16) _Float16 PT[180*24];
    const int tid = threadIdx.x;
    const int lane = tid & 63, wv = tid >> 6;
    const int l15 = lane & 15, l4 = lane >> 4;
    const int x0 = blockIdx.x*16, y0 = blockIdx.y*8;
    const int nb = blockIdx.z;

    int s_pos[2], s_gy[2], s_gx[2], s_oct[2];
    bool s_ok[2], s_act[2];
    #pragma unroll
    for (int it = 0; it < 2; ++it) {
        int task = tid + it*256;
        s_act[it] = (task < 360);
        int pos = task >> 1, oct = task & 1;
        int py = pos / 18, pxx = pos - py*18;
        int gy = y0 - 1 + py, gx = x0 - 1 + pxx;
        s_pos[it] = pos; s_oct[it] = oct;
        s_gy[it] = gy; s_gx[it] = gx;
        s_ok[it] = (gy >= 0) & (gy < HH) & (gx >= 0) & (gx < WW) & s_act[it];
    }
    const _Float16* fbase = fhf + (size_t)nb * HWSZ * 64;

    half8v sv0 = h8zero(), sv1 = h8zero();
    if (s_ok[0]) sv0 = *(const half8v*)&fbase[((size_t)(s_gy[0]*WW + s_gx[0]))*64 + s_oct[0]*8];
    if (s_ok[1]) sv1 = *(const half8v*)&fbase[((size_t)(s_gy[1]*WW + s_gx[1]))*64 + s_oct[1]*8];

    half8v w2f[2][4];
    #pragma unroll
    for (int kc = 0; kc < 2; ++kc)
        #pragma unroll
        for (int mf = 0; mf < 4; ++mf)
            w2f[kc][mf] = *(const half8v*)(w2a + (size_t)((kc*4 + mf)*64 + lane)*8);

    f32x4 b2v[4];
    #pragma unroll
    for (int mf = 0; mf < 4; ++mf)
        #pragma unroll
        for (int i = 0; i < 4; ++i) {
            int row = mf*16 + l4*4 + i;
            b2v[mf][i] = (row < 54) ? b2[row] : 0.f;
        }

    #pragma unroll
    for (int nf = 0; nf < 2; ++nf) {
        int r = wv*2 + nf;
        int y = y0 + r, x = x0 + l15;
        const _Float16* tp = tH + ((size_t)nb*HWSZ + y*WW + x) * 64;
        half8v tf0 = *(const half8v*)&tp[l4*8];
        half8v tf1 = *(const half8v*)&tp[32 + l4*8];
        int px = r*16 + l15;
        #pragma unroll
        for (int mf = 0; mf < 4; ++mf) {
            f32x4 ab = (f32x4){0.f, 0.f, 0.f, 0.f};
            ab = __builtin_amdgcn_mfma_f32_16x16x32_f16(w2f[0][mf], tf0, ab, 0, 0, 0);
            ab = __builtin_amdgcn_mfma_f32_16x16x32_f16(w2f[1][mf], tf1, ab, 0, 0, 0);
            if (mf < 3 || l4 < 2) {
                #pragma unroll
                for (int i = 0; i < 4; ++i) {
                    int jb = mf*16 + l4*4 + i;
                    int m = jb / 9;
                    int tap = jb - m*9;
                    BSH[px*72 + tap*8 + (m & 1)*4 + (m >> 1)] = (_Float16)(ab[i] + b2v[mf][i]);
                }
            }
        }
    }

    const int m0 = l4 >> 1;
    const int c08 = (l4 & 1) * 8;
    #pragma unroll
    for (int it = 0; it < 2; ++it) {
        if (s_act[it])
            *(half8v*)&PT[s_pos[it]*24 + s_oct[it]*8] = (it ? sv1 : sv0);
    }
    __syncthreads();

    f32x4 acc[4][2];
    #pragma unroll
    for (int m = 0; m < 4; ++m)
        #pragma unroll
        for (int nf = 0; nf < 2; ++nf)
            acc[m][nf] = (f32x4){0.f, 0.f, 0.f, 0.f};

    #pragma unroll 1
    for (int cg = 0; cg < 4; ++cg) {
        half8v nv0 = h8zero(), nv1 = h8zero();
        if (cg < 3) {
            int chb = (cg + 1)*16;
            if (s_ok[0]) nv0 = *(const half8v*)&fbase[((size_t)(s_gy[0]*WW + s_gx[0]))*64 + chb + s_oct[0]*8];
            if (s_ok[1]) nv1 = *(const half8v*)&fbase[((size_t)(s_gy[1]*WW + s_gx[1]))*64 + chb + s_oct[1]*8];
        }

        #pragma unroll
        for (int nf = 0; nf < 2; ++nf) {
            int r = wv*2 + nf;
            int px = r*16 + l15;
            half2v s2[3][4];
            #pragma unroll
            for (int ch = 0; ch < 3; ++ch)
                #pragma unroll
                for (int q = 0; q < 4; ++q)
                    s2[ch][q] = (half2v){(_Float16)0.f, (_Float16)0.f};

            #pragma unroll
            for (int tap = 0; tap < 9; ++tap) {
                int ky = tap / 3, kx = tap - ky*3;
                int pos = (r + ky)*18 + l15 + kx;
                half8v pt = *(const half8v*)&PT[pos*24 + c08];
                half4v bv = *(const half4v*)&BSH[px*72 + tap*8 + m0*4];
                half2v b0 = (half2v){bv[0], bv[0]};
                half2v b1 = (half2v){bv[1], bv[1]};
                half2v bx = (half2v){bv[2], bv[2]};
                #pragma unroll
                for (int q = 0; q < 4; ++q) {
                    half2v pq = (half2v){pt[2*q], pt[2*q + 1]};
                    s2[0][q] = pq * b0 + s2[0][q];
                    s2[1][q] = pq * b1 + s2[1][q];
                    s2[2][q] = pq * bx + s2[2][q];
                }
            }
            half8v B0, B1, B2;
            #pragma unroll
            for (int q = 0; q < 4; ++q) {
                B0[2*q] = s2[0][q][0]; B0[2*q+1] = s2[0][q][1];
                B1[2*q] = s2[1][q][0]; B1[2*q+1] = s2[1][q][1];
                B2[2*q] = s2[2][q][0]; B2[2*q+1] = s2[2][q][1];
            }
            #pragma unroll
            for (int hf = 0; hf < 2; ++hf) {
                half8v CAh[3][2];
                #pragma unroll
                for (int ch = 0; ch < 3; ++ch)
                    #pragma unroll
                    for (int o = 0; o < 2; ++o)
                        CAh[ch][o] = *(const half8v*)(coefa +
                            (size_t)(((cg*3 + ch)*4 + hf*2 + o)*64 + lane)*8);
                #pragma unroll
                for (int o = 0; o < 2; ++o) {
                    int oc = hf*2 + o;
                    acc[oc][nf] = __builtin_amdgcn_mfma_f32_16x16x32_f16(CAh[0][o], B0, acc[oc][nf], 0, 0, 0);
                    acc[oc][nf] = __builtin_amdgcn_mfma_f32_16x16x32_f16(CAh[1][o], B1, acc[oc][nf], 0, 0, 0);
                    acc[oc][nf] = __builtin_amdgcn_mfma_f32_16x16x32_f16(CAh[2][o], B2, acc[oc][nf], 0, 0, 0);
                }
            }
        }

        if (cg < 3) {
            __syncthreads();
            #pragma unroll
            for (int it = 0; it < 2; ++it) {
                if (s_act[it])
                    *(half8v*)&PT[s_pos[it]*24 + s_oct[it]*8] = (it ? nv1 : nv0);
            }
            __syncthreads();
        }
    }

    #pragma unroll
    for (int nf = 0; nf < 2; ++nf) {
        int y = y0 + wv*2 + nf, x = x0 + l15;
        _Float16* up = uH + ((size_t)nb*HWSZ + y*WW + x) * 64;
        #pragma unroll
        for (int ocf = 0; ocf < 4; ++ocf) {
            half4v hv;
            #pragma unroll
            for (int i = 0; i < 4; ++i) {
                int co = ocf*16 + l4*4 + i;
                hv[i] = (_Float16)fmaxf(acc[ocf][nf][i]*bn[co] + bn[64 + co], 0.f);
            }
            *(half4v*)&up[ocf*16 + l4*4] = hv;
        }
    }
}

extern "C" void kernel_launch(void* const* d_in, const int* in_sizes, int n_in,
                              void* d_out, int out_size, void* d_ws, size_t ws_size,
                              hipStream_t stream) {
    const float* feat      = (const float*)d_in[0];
    const float* wgt       = (const float*)d_in[1];
    const float* w1        = (const float*)d_in[2];
    const float* b1        = (const float*)d_in[3];
    const float* w2        = (const float*)d_in[4];
    const float* b2        = (const float*)d_in[5];
    const float* coef      = (const float*)d_in[6];
    const float* coef_bias = (const float*)d_in[7];
    const float* brg       = (const float*)d_in[8];
    const float* brb       = (const float*)d_in[9];
    const float* brm       = (const float*)d_in[10];
    const float* brv       = (const float*)d_in[11];
    const float* w3        = (const float*)d_in[12];
    const float* g3        = (const float*)d_in[13];
    const float* b3        = (const float*)d_in[14];
    const float* m3        = (const float*)d_in[15];
    const float* v3        = (const float*)d_in[16];

    float* out = (float*)d_out;
    _Float16* tH = (_Float16*)d_out;
    float* ws  = (float*)d_ws;
    _Float16* hw = (_Float16*)ws;
    _Float16* FHf = hw + OFF_FHF/2;
    _Float16* FHw = hw + OFF_FHW/2;

    nhwc_k<<<dim3(5, 240, 4), 256, 0, stream>>>(feat, wgt, FHf, FHw,
        w1, w3, w2, coef, coef_bias, brg, brb, brm, brv, g3, b3, m3, v3, ws);

    dim3 grid(WW/16, HH/8, NN);   // (20, 30, 2) = 1200 blocks

    if (ws_size >= (size_t)WS_FUSED) {
        // FUSED path: t stays in LDS; u -> disjoint OFF_U region
        _Float16* U = hw + OFF_U/2;
        c1f2_k<<<grid, 256, 0, stream>>>(FHf, FHw, hw + OFF_BW1/2, b1,
            hw + OFF_W2A/2, b2, hw + OFF_COEFA/2, ws + OFF_BN/4, U);
        convmfma_k<2, true><<<grid, 256, 0, stream>>>(
            U, U, hw + OFF_BW3/2,
            ws + OFF_BN/4 + 128, ws + OFF_BN/4 + 192, out, nullptr);
    } else {
        // FALLBACK (R20, known-good): t -> d_out; u -> FHw
        convmfma_k<4, false><<<grid, 256, 0, stream>>>(
            FHf, FHw, hw + OFF_BW1/2, b1, b1, nullptr, tH);
        fuse2_k<<<grid, 256, 0, stream>>>(FHf, tH,
            hw + OFF_W2A/2, b2, hw + OFF_COEFA/2, ws + OFF_BN/4, FHw);
        convmfma_k<2, true><<<grid, 256, 0, stream>>>(
            FHw, FHw, hw + OFF_BW3/2,
            ws + OFF_BN/4 + 128, ws + OFF_BN/4 + 192, out, nullptr);
    }
}